// Round 14
// baseline (96.384 us; speedup 1.0000x reference)
//
#include <hip/hip_runtime.h>
#include <math.h>

#define NN 4096
#define TPB 512
#define SPT 8               // steps per thread
#define NW (TPB / 64)       // 8 waves
#define ALPHA 0.1f
#define DT 0.01f
#define DIFF 10.0f
#define EPS 1e-9f
#define HB 1.5707963267948966f
#define MAXS 520            // > 513 = provable bitwise-exact cap (triangular dep)

__global__ __launch_bounds__(TPB, 2) void cpg_kernel(
    const float* __restrict__ phase, const float* __restrict__ amp,
    const float* __restrict__ w, const float* __restrict__ ha,
    const float* __restrict__ bvec, const float* __restrict__ xy,
    const float* __restrict__ xydo, float* __restrict__ out) {
  // double-buffered cross-wave totals: read [s&1], write [s&1^1]; the single
  // end-of-sweep barrier separates this sweep's writes from next sweep's reads.
  __shared__ float totU[2][8], totV[2][8];
  __shared__ float redU[NW], redV[NW];
  const int tid = threadIdx.x;
  const int lane = tid & 63;
  const int wid = tid >> 6;
  const int g0 = tid * SPT;

  // ---- prep: per-thread constants for its 8 contiguous steps ----
  float ci[SPT], si[SPT], cid[SPT], sid[SPT], axx[SPT], ayy[SPT];
  float xlo[SPT], xhi[SPT], ylo[SPT], yhi[SPT], ae[SPT], be[SPT];
  float u0 = 0.f, v0 = 0.f;
#pragma unroll
  for (int k = 0; k < SPT; ++k) {
    int i = g0 + k;
    float s_, c_;
    sincosf(phase[i], &s_, &c_);       // precise (native sin/cos failed R10)
    float2 p = ((const float2*)xy)[i];
    float2 d = ((const float2*)xydo)[i];
    float r2 = fmaf(p.x, p.x, p.y * p.y);
    float ta = ALPHA * (1.f - r2 * r2);
    float zeta = 1.f - ha[i] * ((d.x + EPS) / (fabsf(d.x) + EPS));
    float tb = w[i] / (zeta + EPS);
    ci[k] = c_; si[k] = s_;
    cid[k] = c_ * DT; sid[k] = s_ * DT;   // pre-scaled increment coeffs
    axx[k] = ta * p.x - tb * p.y - p.x;
    ayy[k] = tb * p.x + ta * p.y - p.y;
    xlo[k] = d.x - DIFF; xhi[k] = d.x + DIFF;
    ylo[k] = d.y - DIFF; yhi[k] = d.y + DIFF;
    float am = amp[i];
    ae[k] = am * DT;                    // out = clamp(ae*cy + be)
    be[k] = fmaf(am, p.y, bvec[i]);
    u0 = fmaf(c_, p.x, fmaf(s_, p.y, u0));
    v0 = fmaf(s_, p.x, fmaf(-c_, p.y, v0));
  }
  // ---- block reduce for initial U0,V0 (deterministic order) ----
#pragma unroll
  for (int off = 32; off; off >>= 1) {
    u0 += __shfl_xor(u0, off, 64);
    v0 += __shfl_xor(v0, off, 64);
  }
  if (lane == 0) { redU[wid] = u0; redV[wid] = v0; }
  if (tid < 8) { totU[0][tid] = 0.f; totV[0][tid] = 0.f; }
  __syncthreads();
  float U0 = 0.f, V0 = 0.f;
#pragma unroll
  for (int ww = 0; ww < NW; ++ww) { U0 += redU[ww]; V0 += redV[ww]; }

  // ---- global Jacobi fixed point: 1 barrier per sweep ----
  float su = 0.f, sv = 0.f, eu = 0.f, ev = 0.f;
  float cy[SPT];
#pragma unroll
  for (int k = 0; k < SPT; ++k) cy[k] = 0.f;

#pragma unroll 1
  for (int s = 0; s < MAXS; ++s) {
    int rb = s & 1;
    // cross-wave carry from previous sweep's totals (wave-uniform selects)
    float cu = 0.f, cv = 0.f;
#pragma unroll
    for (int ww = 0; ww < NW - 1; ++ww) {
      if (wid > ww) { cu += totU[rb][ww]; cv += totV[rb][ww]; }
    }
    float bu = U0 + cu + eu;     // U at this thread's segment start
    float bv = V0 + cv + ev;
    float nsu = 0.f, nsv = 0.f;
    bool chg = false;
#pragma unroll
    for (int k = 0; k < SPT; ++k) {  // exact serial inside segment
      float Uc = bu + nsu, Vc = bv + nsv;
      float xd = fmaf(ci[k], Uc, fmaf(si[k], Vc, axx[k]));
      float yd = fmaf(si[k], Uc, fmaf(-ci[k], Vc, ayy[k]));
      float cx = __builtin_amdgcn_fmed3f(xd, xlo[k], xhi[k]);
      float cyk = __builtin_amdgcn_fmed3f(yd, ylo[k], yhi[k]);
      nsu = fmaf(cid[k], cx, fmaf(sid[k], cyk, nsu));
      nsv = fmaf(sid[k], cx, fmaf(-cid[k], cyk, nsv));
      chg = chg || (cyk != cy[k]);
      cy[k] = cyk;
    }
    chg = chg || (nsu != su) || (nsv != sv);
    su = nsu; sv = nsv;

    // exclusive wave-prefix of (su,sv) — proven shift-first form (no
    // self-coupling through rounding, unlike incl-minus-own shortcut)
    eu = __shfl_up(su, 1, 64); if (lane == 0) eu = 0.f;
    ev = __shfl_up(sv, 1, 64); if (lane == 0) ev = 0.f;
#pragma unroll
    for (int o = 1; o < 64; o <<= 1) {
      float tu = __shfl_up(eu, o, 64);
      float tv = __shfl_up(ev, o, 64);
      eu += (lane >= o) ? tu : 0.f;
      ev += (lane >= o) ? tv : 0.f;
    }
    if (lane == 63) {                    // wave totals -> other buffer
      totU[rb ^ 1][wid] = eu + su;
      totV[rb ^ 1][wid] = ev + sv;
    }
    if (__syncthreads_count((int)chg) == 0) break;  // all bitwise stable
  }

  // ---- epilogue: per-thread constants, coalesced float4 stores ----
  float res[SPT];
#pragma unroll
  for (int k = 0; k < SPT; ++k) {
    float ang = fmaf(ae[k], cy[k], be[k]);
    res[k] = fminf(fmaxf(ang, -HB), HB);
  }
  ((float4*)out)[tid * 2 + 0] = make_float4(res[0], res[1], res[2], res[3]);
  ((float4*)out)[tid * 2 + 1] = make_float4(res[4], res[5], res[6], res[7]);
}

extern "C" void kernel_launch(void* const* d_in, const int* in_sizes, int n_in,
                              void* d_out, int out_size, void* d_ws, size_t ws_size,
                              hipStream_t stream) {
  const float* phase = (const float*)d_in[0];
  const float* amp   = (const float*)d_in[1];
  const float* w     = (const float*)d_in[2];
  const float* ha    = (const float*)d_in[3];
  const float* b     = (const float*)d_in[4];
  const float* xy    = (const float*)d_in[5];
  const float* xydo  = (const float*)d_in[6];
  float* out = (float*)d_out;

  cpg_kernel<<<1, TPB, 0, stream>>>(phase, amp, w, ha, b, xy, xydo, out);
}